// Round 19
// baseline (52.473 us; speedup 1.0000x reference)
//
#include <hip/hip_runtime.h>
#include <hip/hip_fp16.h>

// Depthwise 3D Gaussian conv (1,3,160,160,160) fp32, K=25, radius=12.
// Separable -> three 1-D passes, fp16 intermediates.
// Round 19: conv_w gets the counted-vmcnt split barrier in spill-safe
// form (r17's race was launch_bounds(256,8) -> VGPR<=32 -> scratch spills
// sharing vmcnt with gll, corrupting the count; no clamp here, ~45 VGPR):
//   issue 5 gll (A=0..2 rows<19, B=3..4) -> vmcnt(2)+barrier ->
//   compute rows 0..15 + store (acc dies, stores don't touch LDS) ->
//   vmcnt(0)+barrier -> compute rows 16..31 + store.
// conv_h / conv_d verbatim r16/r18 (replay-proven).

#define NV 160
constexpr int KS    = 25;
constexpr int RAD   = 12;
constexpr int PLANE = NV * NV;        // 25600
constexpr int VOL   = NV * NV * NV;   // 4,096,000
constexpr int TOT   = 3 * VOL;        // 12,288,000

// W-pass geometry (row-major gll)
constexpr int WR    = 32;             // h rows per block
constexpr int OPT   = 10;
constexpr int WIN   = OPT + KS - 1;   // 34

// H/D-pass geometry (full-w tiles, unpadded for gll)
constexpr int HC2    = 80;            // outputs per block along conv axis
constexpr int TR     = 104;           // tile rows (80 + 2*12)
constexpr int TPW    = 80;            // half2 per row (NO pad; 320 B/row)
constexpr int VROWS  = 92;            // valid (non-zero) rows per tile
constexpr int VSLOTS = VROWS * 20;    // 1840 16B slots
constexpr int ZSLOTS = 12 * 20;       // 240 16B zero slots

#define GWS(t) gs[(t) < 13 ? (t) : 24 - (t)]

__device__ __forceinline__ void pk(float2& a, float2 g, float2 v) {
    asm("v_pk_fma_f32 %0, %1, %2, %0" : "+v"(a) : "v"(g), "v"(v));
}

// Recover g1[t] from k3: g1[t] = g3[t,12,12] / cbrt(g3[12,12,12])^2 (exact).
__device__ __forceinline__ void load_g(const float* __restrict__ k3, float* g) {
    float c   = k3[12 * 625 + 312];          // g1[12]^3
    float g12 = cbrtf(c);
    float inv = 1.0f / (g12 * g12);
#pragma unroll
    for (int t = 0; t < KS; ++t) g[t] = k3[t * 625 + 312] * inv;
}

// symmetric half only (13 values)
__device__ __forceinline__ void load_g13(const float* __restrict__ k3, float* g) {
    float c   = k3[12 * 625 + 312];
    float g12 = cbrtf(c);
    float inv = 1.0f / (g12 * g12);
#pragma unroll
    for (int t = 0; t < 13; ++t) g[t] = k3[t * 625 + 312] * inv;
}

__device__ __forceinline__ void gll16(const void* g, void* l) {
    __builtin_amdgcn_global_load_lds(
        (const __attribute__((address_space(1))) void*)g,
        (__attribute__((address_space(3))) void*)l, 16, 0, 0);
}

// ---------------- W pass: f32 in -> f16 out (gll + safe split) ----------
__global__ __launch_bounds__(256) void conv_w(const float* __restrict__ in,
                                              __half* __restrict__ out,
                                              const float* __restrict__ k3) {
    __shared__ float X[WR][NV];              // 32*640 = 20480 B, flat
    float gs[13];
    load_g13(k3, gs);

    int tid = threadIdx.x;
    int b   = blockIdx.x;
    int hc  = b % 5;
    int cd  = b / 5;               // c*160 + d
    int h0  = hc * WR;
    const char* gsrc = (const char*)(in + (size_t)cd * PLANE + (size_t)h0 * NV);
    char* Xf = (char*)(&X[0][0]);
    int wavebase = tid & ~63;

    // 1280 slots of 16B; A = issues 0..2 (slots < 768 -> rows < 19.2)
#pragma unroll
    for (int it = 0; it < 5; ++it) {
        int sw = it * 256 + wavebase;
        gll16(gsrc + (size_t)(sw + (tid & 63)) * 16, Xf + sw * 16);
    }
    asm volatile("s_waitcnt vmcnt(2)" ::: "memory");
    __builtin_amdgcn_s_barrier();
    __builtin_amdgcn_sched_barrier(0);

    int c  = tid & 15;             // w-chunk
    int rr = tid >> 4;             // 0..15

    // ---- phase 1: row rr (rows 0..15, inside A) + immediate store ----
    {
        float acc[OPT];
#pragma unroll
        for (int j = 0; j < OPT; ++j) acc[j] = 0.f;
#pragma unroll
        for (int it = 0; it < WIN; ++it) {
            int wq = c * OPT + it - RAD;         // -12..171
            int wc = min(max(wq, 0), NV - 1);
            float v = X[rr][wc];
            v = (wq == wc) ? v : 0.f;
#pragma unroll
            for (int j = 0; j < OPT; ++j) {
                int t = it - j;
                if (t >= 0 && t < KS) acc[j] = fmaf(GWS(t), v, acc[j]);
            }
        }
        __half* ob = out + (size_t)cd * PLANE + (size_t)(h0 + rr) * NV + c * OPT;
#pragma unroll
        for (int j = 0; j < OPT / 2; ++j)
            *(__half2*)(ob + 2 * j) =
                __float22half2_rn(make_float2(acc[2 * j], acc[2 * j + 1]));
    }
    __builtin_amdgcn_sched_barrier(0);
    asm volatile("s_waitcnt vmcnt(0)" ::: "memory");
    __builtin_amdgcn_s_barrier();
    __builtin_amdgcn_sched_barrier(0);

    // ---- phase 2: row rr+16 ----
    {
        float acc[OPT];
#pragma unroll
        for (int j = 0; j < OPT; ++j) acc[j] = 0.f;
#pragma unroll
        for (int it = 0; it < WIN; ++it) {
            int wq = c * OPT + it - RAD;
            int wc = min(max(wq, 0), NV - 1);
            float v = X[rr + 16][wc];
            v = (wq == wc) ? v : 0.f;
#pragma unroll
            for (int j = 0; j < OPT; ++j) {
                int t = it - j;
                if (t >= 0 && t < KS) acc[j] = fmaf(GWS(t), v, acc[j]);
            }
        }
        __half* ob = out + (size_t)cd * PLANE + (size_t)(h0 + rr + 16) * NV + c * OPT;
#pragma unroll
        for (int j = 0; j < OPT / 2; ++j)
            *(__half2*)(ob + 2 * j) =
                __float22half2_rn(make_float2(acc[2 * j], acc[2 * j + 1]));
    }
}

// ---------------- H pass: f16 in -> f16 out (r16, gll + split) ----------
__global__ __launch_bounds__(320) void conv_h(const __half* __restrict__ in,
                                              __half* __restrict__ out,
                                              const float* __restrict__ k3) {
    __shared__ __half2 T[TR][TPW];           // 104*320 = 33280 B, flat
    float gsv[KS];
    load_g(k3, gsv);
    float2 g2[KS];
#pragma unroll
    for (int t = 0; t < KS; ++t) g2[t] = make_float2(gsv[t], gsv[t]);

    int tid = threadIdx.x;
    int b   = blockIdx.x;
    int hh  = b & 1;
    int cd  = b >> 1;              // c*160 + d
    int h0  = hh * HC2;
    char* Tf = (char*)(&T[0][0]);

    int zbase = (hh == 0) ? 0 : 92 * 320;
    if (tid < ZSLOTS)
        *(uint4*)(Tf + zbase + tid * 16) = make_uint4(0u, 0u, 0u, 0u);

    int vbase = (hh == 0) ? 12 * 320 : 0;
    const char* gsrc = (const char*)(in + (size_t)cd * PLANE
                                     + (size_t)((hh == 0) ? 0 : 68) * NV);
    int wavebase = tid & ~63;
#pragma unroll
    for (int it = 0; it < 4; ++it) {
        int sw = it * 320 + wavebase;
        gll16(gsrc + (size_t)(sw + (tid & 63)) * 16, Tf + vbase + sw * 16);
    }
#pragma unroll
    for (int it = 4; it < 6; ++it) {
        int slot = it * 320 + tid;
        if (slot < VSLOTS) {
            int sw = it * 320 + wavebase;
            gll16(gsrc + (size_t)slot * 16, Tf + vbase + sw * 16);
        }
    }
    asm volatile("s_waitcnt vmcnt(2) lgkmcnt(0)" ::: "memory");
    __builtin_amdgcn_s_barrier();
    __builtin_amdgcn_sched_barrier(0);

    int wp = tid % 80, oc = tid / 80;        // wp 0..79, oc 0..3
    {
        int rb = oc * OPT;
        float2 acc[OPT];
#pragma unroll
        for (int j = 0; j < OPT; ++j) acc[j] = make_float2(0.f, 0.f);
#pragma unroll
        for (int it = 0; it < WIN; ++it) {
            float2 v = __half22float2(T[rb + it][wp]);
#pragma unroll
            for (int j = 0; j < OPT; ++j) {
                int t = it - j;
                if (t >= 0 && t < KS) pk(acc[j], g2[t], v);
            }
        }
        __half* op = out + (size_t)cd * PLANE + (size_t)(h0 + rb) * NV + 2 * wp;
#pragma unroll
        for (int j = 0; j < OPT; ++j)
            *(__half2*)(op + j * NV) = __float22half2_rn(acc[j]);
    }
    __builtin_amdgcn_sched_barrier(0);
    asm volatile("s_waitcnt vmcnt(0)" ::: "memory");
    __builtin_amdgcn_s_barrier();
    __builtin_amdgcn_sched_barrier(0);
    {
        int rb = (oc + 4) * OPT;
        float2 acc[OPT];
#pragma unroll
        for (int j = 0; j < OPT; ++j) acc[j] = make_float2(0.f, 0.f);
#pragma unroll
        for (int it = 0; it < WIN; ++it) {
            float2 v = __half22float2(T[rb + it][wp]);
#pragma unroll
            for (int j = 0; j < OPT; ++j) {
                int t = it - j;
                if (t >= 0 && t < KS) pk(acc[j], g2[t], v);
            }
        }
        __half* op = out + (size_t)cd * PLANE + (size_t)(h0 + rb) * NV + 2 * wp;
#pragma unroll
        for (int j = 0; j < OPT; ++j)
            *(__half2*)(op + j * NV) = __float22half2_rn(acc[j]);
    }
}

// ---------------- D pass: f16 in -> f32 out (r16, gll + split) ----------
__global__ __launch_bounds__(320) void conv_d(const __half* __restrict__ in,
                                              float* __restrict__ out,
                                              const float* __restrict__ k3) {
    __shared__ __half2 T[TR][TPW];           // 33280 B, flat
    float gsv[KS];
    load_g(k3, gsv);
    float2 g2[KS];
#pragma unroll
    for (int t = 0; t < KS; ++t) g2[t] = make_float2(gsv[t], gsv[t]);

    int tid = threadIdx.x;
    int b   = blockIdx.x;
    int dh  = b & 1;
    int ch  = b >> 1;              // c*160 + h
    int c   = ch / NV, h = ch % NV;
    int d0  = dh * HC2;
    char* Tf = (char*)(&T[0][0]);

    int zbase = (dh == 0) ? 0 : 92 * 320;
    if (tid < ZSLOTS)
        *(uint4*)(Tf + zbase + tid * 16) = make_uint4(0u, 0u, 0u, 0u);

    int vbase = (dh == 0) ? 12 * 320 : 0;
    int dg0   = (dh == 0) ? 0 : 68;
    const char* gd = (const char*)(in + (size_t)c * VOL + h * NV
                                   + (size_t)dg0 * PLANE);
    int wavebase = tid & ~63;
#pragma unroll
    for (int it = 0; it < 4; ++it) {
        int slot = it * 320 + tid;
        int rr = slot / 20, cc = slot % 20;
        int sw = it * 320 + wavebase;
        gll16(gd + (size_t)rr * (PLANE * 2) + cc * 16, Tf + vbase + sw * 16);
    }
#pragma unroll
    for (int it = 4; it < 6; ++it) {
        int slot = it * 320 + tid;
        if (slot < VSLOTS) {
            int rr = slot / 20, cc = slot % 20;
            int sw = it * 320 + wavebase;
            gll16(gd + (size_t)rr * (PLANE * 2) + cc * 16, Tf + vbase + sw * 16);
        }
    }
    asm volatile("s_waitcnt vmcnt(2) lgkmcnt(0)" ::: "memory");
    __builtin_amdgcn_s_barrier();
    __builtin_amdgcn_sched_barrier(0);

    int wp = tid % 80, oc = tid / 80;
    {
        int rb = oc * OPT;
        float2 acc[OPT];
#pragma unroll
        for (int j = 0; j < OPT; ++j) acc[j] = make_float2(0.f, 0.f);
#pragma unroll
        for (int it = 0; it < WIN; ++it) {
            float2 v = __half22float2(T[rb + it][wp]);
#pragma unroll
            for (int j = 0; j < OPT; ++j) {
                int t = it - j;
                if (t >= 0 && t < KS) pk(acc[j], g2[t], v);
            }
        }
        float* op = out + (size_t)c * VOL + h * NV + 2 * wp;
#pragma unroll
        for (int j = 0; j < OPT; ++j)
            *(float2*)(op + (size_t)(d0 + rb + j) * PLANE) = acc[j];
    }
    __builtin_amdgcn_sched_barrier(0);
    asm volatile("s_waitcnt vmcnt(0)" ::: "memory");
    __builtin_amdgcn_s_barrier();
    __builtin_amdgcn_sched_barrier(0);
    {
        int rb = (oc + 4) * OPT;
        float2 acc[OPT];
#pragma unroll
        for (int j = 0; j < OPT; ++j) acc[j] = make_float2(0.f, 0.f);
#pragma unroll
        for (int it = 0; it < WIN; ++it) {
            float2 v = __half22float2(T[rb + it][wp]);
#pragma unroll
            for (int j = 0; j < OPT; ++j) {
                int t = it - j;
                if (t >= 0 && t < KS) pk(acc[j], g2[t], v);
            }
        }
        float* op = out + (size_t)c * VOL + h * NV + 2 * wp;
#pragma unroll
        for (int j = 0; j < OPT; ++j)
            *(float2*)(op + (size_t)(d0 + rb + j) * PLANE) = acc[j];
    }
}

// Fallback (only if ws too small): direct 25^3-tap depthwise conv.
__global__ __launch_bounds__(256) void conv3d_direct(const float* __restrict__ x,
                                                     const float* __restrict__ k3,
                                                     float* __restrict__ out) {
    int idx = blockIdx.x * 256 + threadIdx.x;
    if (idx >= TOT) return;
    int w = idx % NV;
    int t = idx / NV;
    int h = t % NV; t /= NV;
    int d = t % NV;
    int c = t / NV;
    const float* kc = k3 + c * (KS * KS * KS);
    float acc = 0.f;
    for (int i = 0; i < KS; ++i) {
        int dd = d + i - RAD;
        if (dd < 0 || dd >= NV) continue;
        for (int j = 0; j < KS; ++j) {
            int hh = h + j - RAD;
            if (hh < 0 || hh >= NV) continue;
            const float* xr = x + (c * NV + dd) * NV * NV + hh * NV + (w - RAD);
            const float* kr = kc + (i * KS + j) * KS;
            int k0 = (RAD - w) > 0 ? (RAD - w) : 0;
            int k1 = (NV + RAD - w) < KS ? (NV + RAD - w) : KS;
            for (int k = k0; k < k1; ++k) acc += kr[k] * xr[k];
        }
    }
    out[idx] = acc;
}

extern "C" void kernel_launch(void* const* d_in, const int* in_sizes, int n_in,
                              void* d_out, int out_size, void* d_ws, size_t ws_size,
                              hipStream_t stream) {
    const float* x  = (const float*)d_in[0];
    const float* k3 = (const float*)d_in[1];
    float* out = (float*)d_out;

    if (ws_size >= (size_t)TOT * 2 * sizeof(__half)) {
        __half* tmpA = (__half*)d_ws;
        __half* tmpB = tmpA + TOT;
        conv_w<<<480 * 5, 256, 0, stream>>>(x, tmpA, k3);     // f32 -> f16 (W)
        conv_h<<<480 * 2, 320, 0, stream>>>(tmpA, tmpB, k3);  // f16 -> f16 (H)
        conv_d<<<480 * 2, 320, 0, stream>>>(tmpB, out, k3);   // f16 -> f32 (D)
    } else {
        conv3d_direct<<<(TOT + 255) / 256, 256, 0, stream>>>(x, k3, out);
    }
}

// Round 20
// 51.840 us; speedup vs baseline: 1.0122x; 1.0122x over previous
//
#include <hip/hip_runtime.h>
#include <hip/hip_fp16.h>

// Depthwise 3D Gaussian conv (1,3,160,160,160) fp32, K=25, radius=12.
// Separable -> three 1-D passes, fp16 intermediates. FINAL (r18 lockin):
//   conv_w: gll row-major staging (contiguous 20.5KB span), plain
//           __syncthreads (split-vmcnt neutral here, r19).
//   conv_h/conv_d: gll staging + counted-vmcnt split barrier (r16, +2.5us).
// History: fusion x5 lost (phase-serialized blocks < streaming passes);
// fp16 intermediates -33% bytes (r7, -12us); gll+split (r16, -2.5us);
// r17's launch_bounds-induced spill corrupted vmcnt counting -> race
// (lesson: never clamp VGPR below need in a counted-vmcnt kernel).

#define NV 160
constexpr int KS    = 25;
constexpr int RAD   = 12;
constexpr int PLANE = NV * NV;        // 25600
constexpr int VOL   = NV * NV * NV;   // 4,096,000
constexpr int TOT   = 3 * VOL;        // 12,288,000

// W-pass geometry (row-major gll)
constexpr int WR    = 32;             // h rows per block
constexpr int OPT   = 10;
constexpr int WIN   = OPT + KS - 1;   // 34

// H/D-pass geometry (full-w tiles, unpadded for gll)
constexpr int HC2    = 80;            // outputs per block along conv axis
constexpr int TR     = 104;           // tile rows (80 + 2*12)
constexpr int TPW    = 80;            // half2 per row (NO pad; 320 B/row)
constexpr int VROWS  = 92;            // valid (non-zero) rows per tile
constexpr int VSLOTS = VROWS * 20;    // 1840 16B slots
constexpr int ZSLOTS = 12 * 20;       // 240 16B zero slots

#define GWS(t) gs[(t) < 13 ? (t) : 24 - (t)]

__device__ __forceinline__ void pk(float2& a, float2 g, float2 v) {
    asm("v_pk_fma_f32 %0, %1, %2, %0" : "+v"(a) : "v"(g), "v"(v));
}

// Recover g1[t] from k3: g1[t] = g3[t,12,12] / cbrt(g3[12,12,12])^2 (exact).
__device__ __forceinline__ void load_g(const float* __restrict__ k3, float* g) {
    float c   = k3[12 * 625 + 312];          // g1[12]^3
    float g12 = cbrtf(c);
    float inv = 1.0f / (g12 * g12);
#pragma unroll
    for (int t = 0; t < KS; ++t) g[t] = k3[t * 625 + 312] * inv;
}

// symmetric half only (13 values)
__device__ __forceinline__ void load_g13(const float* __restrict__ k3, float* g) {
    float c   = k3[12 * 625 + 312];
    float g12 = cbrtf(c);
    float inv = 1.0f / (g12 * g12);
#pragma unroll
    for (int t = 0; t < 13; ++t) g[t] = k3[t * 625 + 312] * inv;
}

__device__ __forceinline__ void gll16(const void* g, void* l) {
    __builtin_amdgcn_global_load_lds(
        (const __attribute__((address_space(1))) void*)g,
        (__attribute__((address_space(3))) void*)l, 16, 0, 0);
}

// ---------------- W pass: f32 in -> f16 out (gll row-major, full drain) ----
__global__ __launch_bounds__(256) void conv_w(const float* __restrict__ in,
                                              __half* __restrict__ out,
                                              const float* __restrict__ k3) {
    __shared__ float X[WR][NV];              // 32*640 = 20480 B, flat
    float gs[13];
    load_g13(k3, gs);

    int tid = threadIdx.x;
    int b   = blockIdx.x;
    int hc  = b % 5;
    int cd  = b / 5;               // c*160 + d
    int h0  = hc * WR;
    const char* gsrc = (const char*)(in + (size_t)cd * PLANE + (size_t)h0 * NV);
    char* Xf = (char*)(&X[0][0]);
    int wavebase = tid & ~63;

    // 1280 slots of 16B; source span fully contiguous (20.5 KB)
#pragma unroll
    for (int it = 0; it < 5; ++it) {
        int sw = it * 256 + wavebase;
        gll16(gsrc + (size_t)(sw + (tid & 63)) * 16, Xf + sw * 16);
    }
    __syncthreads();                         // full drain: proven-safe

    int c  = tid & 15;             // w-chunk
    int rr = tid >> 4;             // 0..15

#pragma unroll
    for (int ph = 0; ph < 2; ++ph) {
        int row = rr + 16 * ph;
        float acc[OPT];
#pragma unroll
        for (int j = 0; j < OPT; ++j) acc[j] = 0.f;
#pragma unroll
        for (int it = 0; it < WIN; ++it) {
            int wq = c * OPT + it - RAD;         // -12..171
            int wc = min(max(wq, 0), NV - 1);
            float v = X[row][wc];
            v = (wq == wc) ? v : 0.f;
#pragma unroll
            for (int j = 0; j < OPT; ++j) {
                int t = it - j;
                if (t >= 0 && t < KS) acc[j] = fmaf(GWS(t), v, acc[j]);
            }
        }
        __half* ob = out + (size_t)cd * PLANE + (size_t)(h0 + row) * NV + c * OPT;
#pragma unroll
        for (int j = 0; j < OPT / 2; ++j)
            *(__half2*)(ob + 2 * j) =
                __float22half2_rn(make_float2(acc[2 * j], acc[2 * j + 1]));
    }
}

// ---------------- H pass: f16 in -> f16 out (r16, gll + split) ----------
__global__ __launch_bounds__(320) void conv_h(const __half* __restrict__ in,
                                              __half* __restrict__ out,
                                              const float* __restrict__ k3) {
    __shared__ __half2 T[TR][TPW];           // 104*320 = 33280 B, flat
    float gsv[KS];
    load_g(k3, gsv);
    float2 g2[KS];
#pragma unroll
    for (int t = 0; t < KS; ++t) g2[t] = make_float2(gsv[t], gsv[t]);

    int tid = threadIdx.x;
    int b   = blockIdx.x;
    int hh  = b & 1;
    int cd  = b >> 1;              // c*160 + d
    int h0  = hh * HC2;
    char* Tf = (char*)(&T[0][0]);

    int zbase = (hh == 0) ? 0 : 92 * 320;
    if (tid < ZSLOTS)
        *(uint4*)(Tf + zbase + tid * 16) = make_uint4(0u, 0u, 0u, 0u);

    int vbase = (hh == 0) ? 12 * 320 : 0;
    const char* gsrc = (const char*)(in + (size_t)cd * PLANE
                                     + (size_t)((hh == 0) ? 0 : 68) * NV);
    int wavebase = tid & ~63;
#pragma unroll
    for (int it = 0; it < 4; ++it) {
        int sw = it * 320 + wavebase;
        gll16(gsrc + (size_t)(sw + (tid & 63)) * 16, Tf + vbase + sw * 16);
    }
#pragma unroll
    for (int it = 4; it < 6; ++it) {
        int slot = it * 320 + tid;
        if (slot < VSLOTS) {
            int sw = it * 320 + wavebase;
            gll16(gsrc + (size_t)slot * 16, Tf + vbase + sw * 16);
        }
    }
    asm volatile("s_waitcnt vmcnt(2) lgkmcnt(0)" ::: "memory");
    __builtin_amdgcn_s_barrier();
    __builtin_amdgcn_sched_barrier(0);

    int wp = tid % 80, oc = tid / 80;        // wp 0..79, oc 0..3
    {
        int rb = oc * OPT;
        float2 acc[OPT];
#pragma unroll
        for (int j = 0; j < OPT; ++j) acc[j] = make_float2(0.f, 0.f);
#pragma unroll
        for (int it = 0; it < WIN; ++it) {
            float2 v = __half22float2(T[rb + it][wp]);
#pragma unroll
            for (int j = 0; j < OPT; ++j) {
                int t = it - j;
                if (t >= 0 && t < KS) pk(acc[j], g2[t], v);
            }
        }
        __half* op = out + (size_t)cd * PLANE + (size_t)(h0 + rb) * NV + 2 * wp;
#pragma unroll
        for (int j = 0; j < OPT; ++j)
            *(__half2*)(op + j * NV) = __float22half2_rn(acc[j]);
    }
    __builtin_amdgcn_sched_barrier(0);
    asm volatile("s_waitcnt vmcnt(0)" ::: "memory");
    __builtin_amdgcn_s_barrier();
    __builtin_amdgcn_sched_barrier(0);
    {
        int rb = (oc + 4) * OPT;
        float2 acc[OPT];
#pragma unroll
        for (int j = 0; j < OPT; ++j) acc[j] = make_float2(0.f, 0.f);
#pragma unroll
        for (int it = 0; it < WIN; ++it) {
            float2 v = __half22float2(T[rb + it][wp]);
#pragma unroll
            for (int j = 0; j < OPT; ++j) {
                int t = it - j;
                if (t >= 0 && t < KS) pk(acc[j], g2[t], v);
            }
        }
        __half* op = out + (size_t)cd * PLANE + (size_t)(h0 + rb) * NV + 2 * wp;
#pragma unroll
        for (int j = 0; j < OPT; ++j)
            *(__half2*)(op + j * NV) = __float22half2_rn(acc[j]);
    }
}

// ---------------- D pass: f16 in -> f32 out (r16, gll + split) ----------
__global__ __launch_bounds__(320) void conv_d(const __half* __restrict__ in,
                                              float* __restrict__ out,
                                              const float* __restrict__ k3) {
    __shared__ __half2 T[TR][TPW];           // 33280 B, flat
    float gsv[KS];
    load_g(k3, gsv);
    float2 g2[KS];
#pragma unroll
    for (int t = 0; t < KS; ++t) g2[t] = make_float2(gsv[t], gsv[t]);

    int tid = threadIdx.x;
    int b   = blockIdx.x;
    int dh  = b & 1;
    int ch  = b >> 1;              // c*160 + h
    int c   = ch / NV, h = ch % NV;
    int d0  = dh * HC2;
    char* Tf = (char*)(&T[0][0]);

    int zbase = (dh == 0) ? 0 : 92 * 320;
    if (tid < ZSLOTS)
        *(uint4*)(Tf + zbase + tid * 16) = make_uint4(0u, 0u, 0u, 0u);

    int vbase = (dh == 0) ? 12 * 320 : 0;
    int dg0   = (dh == 0) ? 0 : 68;
    const char* gd = (const char*)(in + (size_t)c * VOL + h * NV
                                   + (size_t)dg0 * PLANE);
    int wavebase = tid & ~63;
#pragma unroll
    for (int it = 0; it < 4; ++it) {
        int slot = it * 320 + tid;
        int rr = slot / 20, cc = slot % 20;
        int sw = it * 320 + wavebase;
        gll16(gd + (size_t)rr * (PLANE * 2) + cc * 16, Tf + vbase + sw * 16);
    }
#pragma unroll
    for (int it = 4; it < 6; ++it) {
        int slot = it * 320 + tid;
        if (slot < VSLOTS) {
            int rr = slot / 20, cc = slot % 20;
            int sw = it * 320 + wavebase;
            gll16(gd + (size_t)rr * (PLANE * 2) + cc * 16, Tf + vbase + sw * 16);
        }
    }
    asm volatile("s_waitcnt vmcnt(2) lgkmcnt(0)" ::: "memory");
    __builtin_amdgcn_s_barrier();
    __builtin_amdgcn_sched_barrier(0);

    int wp = tid % 80, oc = tid / 80;
    {
        int rb = oc * OPT;
        float2 acc[OPT];
#pragma unroll
        for (int j = 0; j < OPT; ++j) acc[j] = make_float2(0.f, 0.f);
#pragma unroll
        for (int it = 0; it < WIN; ++it) {
            float2 v = __half22float2(T[rb + it][wp]);
#pragma unroll
            for (int j = 0; j < OPT; ++j) {
                int t = it - j;
                if (t >= 0 && t < KS) pk(acc[j], g2[t], v);
            }
        }
        float* op = out + (size_t)c * VOL + h * NV + 2 * wp;
#pragma unroll
        for (int j = 0; j < OPT; ++j)
            *(float2*)(op + (size_t)(d0 + rb + j) * PLANE) = acc[j];
    }
    __builtin_amdgcn_sched_barrier(0);
    asm volatile("s_waitcnt vmcnt(0)" ::: "memory");
    __builtin_amdgcn_s_barrier();
    __builtin_amdgcn_sched_barrier(0);
    {
        int rb = (oc + 4) * OPT;
        float2 acc[OPT];
#pragma unroll
        for (int j = 0; j < OPT; ++j) acc[j] = make_float2(0.f, 0.f);
#pragma unroll
        for (int it = 0; it < WIN; ++it) {
            float2 v = __half22float2(T[rb + it][wp]);
#pragma unroll
            for (int j = 0; j < OPT; ++j) {
                int t = it - j;
                if (t >= 0 && t < KS) pk(acc[j], g2[t], v);
            }
        }
        float* op = out + (size_t)c * VOL + h * NV + 2 * wp;
#pragma unroll
        for (int j = 0; j < OPT; ++j)
            *(float2*)(op + (size_t)(d0 + rb + j) * PLANE) = acc[j];
    }
}

// Fallback (only if ws too small): direct 25^3-tap depthwise conv.
__global__ __launch_bounds__(256) void conv3d_direct(const float* __restrict__ x,
                                                     const float* __restrict__ k3,
                                                     float* __restrict__ out) {
    int idx = blockIdx.x * 256 + threadIdx.x;
    if (idx >= TOT) return;
    int w = idx % NV;
    int t = idx / NV;
    int h = t % NV; t /= NV;
    int d = t % NV;
    int c = t / NV;
    const float* kc = k3 + c * (KS * KS * KS);
    float acc = 0.f;
    for (int i = 0; i < KS; ++i) {
        int dd = d + i - RAD;
        if (dd < 0 || dd >= NV) continue;
        for (int j = 0; j < KS; ++j) {
            int hh = h + j - RAD;
            if (hh < 0 || hh >= NV) continue;
            const float* xr = x + (c * NV + dd) * NV * NV + hh * NV + (w - RAD);
            const float* kr = kc + (i * KS + j) * KS;
            int k0 = (RAD - w) > 0 ? (RAD - w) : 0;
            int k1 = (NV + RAD - w) < KS ? (NV + RAD - w) : KS;
            for (int k = k0; k < k1; ++k) acc += kr[k] * xr[k];
        }
    }
    out[idx] = acc;
}

extern "C" void kernel_launch(void* const* d_in, const int* in_sizes, int n_in,
                              void* d_out, int out_size, void* d_ws, size_t ws_size,
                              hipStream_t stream) {
    const float* x  = (const float*)d_in[0];
    const float* k3 = (const float*)d_in[1];
    float* out = (float*)d_out;

    if (ws_size >= (size_t)TOT * 2 * sizeof(__half)) {
        __half* tmpA = (__half*)d_ws;
        __half* tmpB = tmpA + TOT;
        conv_w<<<480 * 5, 256, 0, stream>>>(x, tmpA, k3);     // f32 -> f16 (W)
        conv_h<<<480 * 2, 320, 0, stream>>>(tmpA, tmpB, k3);  // f16 -> f16 (H)
        conv_d<<<480 * 2, 320, 0, stream>>>(tmpB, out, k3);   // f16 -> f32 (D)
    } else {
        conv3d_direct<<<(TOT + 255) / 256, 256, 0, stream>>>(x, k3, out);
    }
}